// Round 8
// baseline (462.010 us; speedup 1.0000x reference)
//
#include <hip/hip_runtime.h>
#include <math.h>

typedef __attribute__((ext_vector_type(8))) __bf16 bf16x8;
typedef __attribute__((ext_vector_type(4))) float f32x4;
typedef __attribute__((ext_vector_type(16))) float f32x16;
typedef __attribute__((ext_vector_type(8))) unsigned short u16x8;
typedef __attribute__((ext_vector_type(8))) int i32x8;

#define GAS(p) ((const __attribute__((address_space(1))) void*)(p))
#define LAS(p) ((__attribute__((address_space(3))) void*)(p))

__device__ __forceinline__ unsigned short f2bf(float f) {
  union { float f; unsigned int u; } v; v.f = f;
  unsigned int r = (v.u + 0x7FFFu + ((v.u >> 16) & 1u)) >> 16;
  return (unsigned short)r;
}
__device__ __forceinline__ float bf2f(unsigned short b) {
  union { unsigned int u; float f; } v; v.u = ((unsigned int)b) << 16;
  return v.f;
}

// ---------------- fused f32 -> bf16 cast ----------------
// z1,z2 -> row-major bf16; w1,w2 -> FRAGMENT-MAJOR bf16 (proj reads B-frags
// directly from global: contiguous 512B per (panel, k-step, half)).
__global__ __launch_bounds__(256) void cast_all_kernel(
    const float* __restrict__ z1, const float* __restrict__ z2,
    const float* __restrict__ w1, const float* __restrict__ w2,
    unsigned short* __restrict__ z1b, unsigned short* __restrict__ z2b,
    unsigned short* __restrict__ w1b, unsigned short* __restrict__ w2b) {
  int b = blockIdx.x;
  if (b < 8192) {
    const float* in = (b < 4096) ? z1 : z2;
    unsigned short* out = (b < 4096) ? z1b : z2b;
    int base = (b < 4096) ? b : b - 4096;
    int i = (base * 256 + threadIdx.x) * 4;
    float4 v = *(const float4*)(in + i);
    ushort4 o;
    o.x = f2bf(v.x); o.y = f2bf(v.y); o.z = f2bf(v.z); o.w = f2bf(v.w);
    *(ushort4*)(out + i) = o;
  } else {
    const float* in = (b < 8448) ? w1 : w2;
    unsigned short* out = (b < 8448) ? w1b : w2b;
    int base = (b < 8448) ? b - 8192 : b - 8448;
    int i = (base * 256 + threadIdx.x) * 4;
    float4 v = *(const float4*)(in + i);
    unsigned int lo = (unsigned)f2bf(v.x) | ((unsigned)f2bf(v.y) << 16);
    unsigned int hi = (unsigned)f2bf(v.z) | ((unsigned)f2bf(v.w) << 16);
    const int col = i >> 9, k = i & 511;
    const size_t dst = (size_t)(col >> 5) * 32768 + (size_t)(k >> 4) * 1024
                     + (size_t)((k >> 3) & 1) * 512 + (col & 31) * 16 + (k & 7) * 2;
    *(int2*)((char*)out + dst) = make_int2((int)lo, (int)hi);
  }
}

// ========== proj (R17): 64x64 tile, A via swizzled LDS, W direct from global ==========
template<int EPI>
__global__ __launch_bounds__(256, 4)
void proj_kernel(const unsigned short* __restrict__ A1,
                 const unsigned short* __restrict__ A2,
                 const unsigned short* __restrict__ Wf,   // fragment-major
                 const float* __restrict__ bias,
                 unsigned short* __restrict__ C1,
                 unsigned short* __restrict__ C2) {
  __shared__ unsigned short lA[2][4096];   // [buf][64 rows x 64 k] swizzled
  const int b = blockIdx.x;
  const int which = b >> 9;
  const int r = b & 511;
  const int m0 = (r >> 3) * 64;
  const int n0 = (r & 7) * 64;
  const unsigned short* A = which ? A2 : A1;
  unsigned short* C = which ? C2 : C1;

  const int tid  = threadIdx.x;
  const int wv   = tid >> 6;
  const int lane = tid & 63;
  const int half = lane >> 5;
  const int l31  = lane & 31;

  const int srow0 = wv * 8 + (lane >> 3);
  const int srow1 = srow0 + 32;
  const int sc0 = ((lane & 7) * 16) ^ ((srow0 & 7) << 4);
  const int sc1 = ((lane & 7) * 16) ^ ((srow1 & 7) << 4);
  const int sdst0 = wv * 1024 + lane * 16;
  const int sdst1 = sdst0 + 4096;
  const char* Ac = (const char*)A;

#define PROJ_STAGE(buf, kc)                                                    \
  do {                                                                         \
    const size_t kb = (size_t)(kc) * 128;                                      \
    __builtin_amdgcn_global_load_lds(                                          \
        GAS(Ac + (size_t)(m0 + srow0) * 1024 + kb + sc0),                      \
        LAS((char*)&lA[buf][0] + sdst0), 16, 0, 0);                            \
    __builtin_amdgcn_global_load_lds(                                          \
        GAS(Ac + (size_t)(m0 + srow1) * 1024 + kb + sc1),                      \
        LAS((char*)&lA[buf][0] + sdst1), 16, 0, 0);                            \
  } while (0)

  const int arow = (wv & 1) * 32 + l31;
  const int aoff = arow * 128;
  const int aswz = (arow & 7) << 4;
  const char* Wb = (const char*)Wf
                 + (size_t)((n0 >> 5) + (wv >> 1)) * 32768
                 + half * 512 + l31 * 16;

  f32x16 acc;
#pragma unroll
  for (int i = 0; i < 16; ++i) acc[i] = 0.f;

  PROJ_STAGE(0, 0);
  __syncthreads();

  for (int kc = 0; kc < 8; ++kc) {
    if (kc < 7) PROJ_STAGE((kc + 1) & 1, kc + 1);
    const char* bufA = (const char*)&lA[kc & 1][0];
#pragma unroll
    for (int s = 0; s < 4; ++s) {
      bf16x8 av = *(const bf16x8*)(bufA + aoff + ((s * 32 + half * 16) ^ aswz));
      bf16x8 bv = *(const bf16x8*)(Wb + (size_t)(kc * 4 + s) * 1024);
      acc = __builtin_amdgcn_mfma_f32_32x32x16_bf16(av, bv, acc, 0, 0, 0);
    }
    __syncthreads();
  }
#undef PROJ_STAGE

  const int col = n0 + (wv >> 1) * 32 + l31;
  const float bvs = bias[col];
#pragma unroll
  for (int reg = 0; reg < 16; ++reg) {
    const int row = m0 + (wv & 1) * 32 + (reg & 3) + 8 * (reg >> 2) + 4 * half;
    float v = acc[reg] + bvs;
    if constexpr (EPI == 0) v = (v > 0.f) ? v : expm1f(v);
    C[(size_t)row * 512 + col] = f2bf(v);
  }
}

// ========== R18 gram: 8-wave 128x128 supertile, acc[1][2], <=128 regs/wave ==========
// The ONE untried occupancy config: R11's per-block structure EXACTLY
// (2112 blocks, same decode, same A staging, same B pair-sharing, same
// total MFMA/loads) but 8 waves of HALF the per-wave work each: wave w =
// 32 rows (A panel w&3) x 64 cols (B panels 2*(w>>2),+1). Registers:
// acc 32 + rs 16 + fb 16 + fa 8 + addr ~30 ~= 110 <= 128 cap at (512,4)
// -> 4 waves/SIMD, 2 blocks/CU (LDS 128<=160 KB). vs R13's failure: block
// count unchanged (no decode/epilogue doubling), B panels shared by 4 waves
// (L1 sharing improves). Latency coverage per SIMD doubles.
// Block map: [0,544) tri1 (q1,d11), [544,1088) tri2 (q2,d22),
//            [1088,2112) cross, b=1088+g*64+row. Tri quads: cum=2q(q+1).
__global__ __launch_bounds__(512, 4)
void gram_kernel(const unsigned char* __restrict__ q1,
                 const unsigned char* __restrict__ q2,
                 float* __restrict__ d11, float* __restrict__ d22,
                 float* __restrict__ d12r, float* __restrict__ d12c) {
  __shared__ unsigned char lA[65536];   // 4 panels x full K (fragment-major)

  const int b = blockIdx.x;
  const unsigned char *Abase, *Bbase;
  float *rptr, *cptr;
  int by, g, cnt;
  bool cross;
  if (b < 1088) {
    const bool first = (b < 544);
    int j = first ? b : b - 544;
    int q = (int)((sqrtf(2.f * j + 1.f) - 1.f) * 0.5f);
    while (2 * (q + 1) * (q + 2) <= j) ++q;
    while (2 * q * (q + 1) > j) --q;
    const int w = j - 2 * q * (q + 1);
    const int dr = w / (q + 1);
    g = w - dr * (q + 1);
    by = 4 * q + dr;
    const unsigned char* h = first ? q1 : q2;
    Abase = h; Bbase = h;
    rptr = first ? d11 : d22; cptr = rptr;
    cnt = min(4, by + 1 - g * 4);
    cross = false;
  } else {
    const int j = b - 1088;
    g = j >> 6; by = j & 63;
    Abase = q1; Bbase = q2;
    rptr = d12r; cptr = d12c;
    cnt = 4; cross = true;
  }

  const int tid  = threadIdx.x;
  const int wv   = tid >> 6;      // 0..7
  const int lane = tid & 63;
  const int half = lane >> 5;
  const int l31  = lane & 31;
  const int rw   = wv & 3;        // A panel (32-row quarter)
  const int cw   = wv >> 2;       // col half (2 B panels)
  const int lfo  = half * 1024 + l31 * 16;

  // ---- stage the full A tile (64 KB) once: 512 threads x 16B x 8 iters ----
  {
    const unsigned char* Asrc = Abase + (size_t)by * 65536 + tid * 16;
    unsigned char* Adst = lA + tid * 16;
#pragma unroll
    for (int i = 0; i < 8; ++i)
      __builtin_amdgcn_global_load_lds(GAS(Asrc + i * 8192),
                                       LAS(Adst + i * 8192), 16, 0, 0);
  }
  __syncthreads();   // only barrier in the kernel

  union frag { i32x8 v; int4 h[2]; };

  float rs[16];
#pragma unroll
  for (int rr = 0; rr < 16; ++rr) rs[rr] = 0.f;

  const unsigned char* Apan = lA + rw * 16384 + lfo;          // this wave's A panel
  const unsigned char* baseB = Bbase + (size_t)(2 * cw) * 16384 + lfo;

  for (int t = 0; t < cnt; ++t) {
    const int ct = g * 4 + t;   // B column supertile
    const unsigned char* B0 = baseB + (size_t)ct * 65536;
    const unsigned char* B1 = B0 + 16384;

    f32x16 acc[2];
#pragma unroll
    for (int ni = 0; ni < 2; ++ni)
#pragma unroll
      for (int rr = 0; rr < 16; ++rr) acc[ni][rr] = 0.f;

#pragma unroll
    for (int KT = 0; KT < 4; ++KT) {
#pragma unroll
      for (int ktl = 0; ktl < 2; ++ktl) {
        const int ko = KT * 4096 + ktl * 2048;
        frag fa, fb[2];
        fb[0].h[0] = *(const int4*)(B0 + ko);
        fb[0].h[1] = *(const int4*)(B0 + ko + 512);
        fb[1].h[0] = *(const int4*)(B1 + ko);
        fb[1].h[1] = *(const int4*)(B1 + ko + 512);
        fa.h[0] = *(const int4*)(Apan + ko);
        fa.h[1] = *(const int4*)(Apan + ko + 512);
#pragma unroll
        for (int ni = 0; ni < 2; ++ni)
          acc[ni] = __builtin_amdgcn_mfma_scale_f32_32x32x64_f8f6f4(
              fa.v, fb[ni].v, acc[ni],
              0, 0,                    // cbsz=e4m3, blgp=e4m3
              0, 0x7F7F7F7F,           // scale_a (E8M0 1.0)
              0, 0x7F7F7F7F);          // scale_b
      }
    }

    // per-tile epilogue: exp, rowsums in regs, colsum atomics
    float cs[2] = {0.f, 0.f};
#pragma unroll
    for (int ni = 0; ni < 2; ++ni)
#pragma unroll
      for (int rr = 0; rr < 16; ++rr) {
        float v = exp2f(2.8853900817779268f * acc[ni][rr]);
        rs[rr] += v;
        cs[ni] += v;
      }
    const bool diag = (!cross) && (ct == by);
    if (!diag) {
#pragma unroll
      for (int ni = 0; ni < 2; ++ni) {
        float v = cs[ni] + __shfl_xor(cs[ni], 32, 64);
        if (half == 0)
          atomicAdd(&cptr[ct * 128 + cw * 64 + ni * 32 + l31], v);
      }
    }
  }

  // rowsum: reduce over 32 column-lanes (within each half), atomics per wave
#pragma unroll
  for (int dd = 1; dd < 32; dd <<= 1) {
#pragma unroll
    for (int rr = 0; rr < 16; ++rr) rs[rr] += __shfl_xor(rs[rr], dd, 64);
  }
  if (l31 == 0) {
    const int mb = by * 128 + rw * 32;
#pragma unroll
    for (int rr = 0; rr < 16; ++rr) {
      const int row = mb + (rr & 3) + 8 * (rr >> 2) + 4 * half;
      atomicAdd(&rptr[row], rs[rr]);
    }
  }
}

// ------- normalize -> fp8 in 32-row-panel FRAGMENT-MAJOR layout + diag dot -------
__global__ __launch_bounds__(256)
void norm_diag_kernel(const unsigned short* __restrict__ h1,
                      const unsigned short* __restrict__ h2,
                      unsigned char* __restrict__ q1,
                      unsigned char* __restrict__ q2,
                      float* __restrict__ cdiag) {
  const int wave = threadIdx.x >> 6, lane = threadIdx.x & 63;
  const int row = blockIdx.x * 4 + wave;
  const u16x8 u1 = *(const u16x8*)(h1 + (size_t)row * 512 + lane * 8);
  const u16x8 u2 = *(const u16x8*)(h2 + (size_t)row * 512 + lane * 8);
  float f1[8], f2[8], ss1 = 0.f, ss2 = 0.f;
#pragma unroll
  for (int j = 0; j < 8; ++j) {
    f1[j] = bf2f(u1[j]); ss1 += f1[j] * f1[j];
    f2[j] = bf2f(u2[j]); ss2 += f2[j] * f2[j];
  }
#pragma unroll
  for (int d = 1; d < 64; d <<= 1) {
    ss1 += __shfl_xor(ss1, d, 64);
    ss2 += __shfl_xor(ss2, d, 64);
  }
  const float inv1 = 1.0f / fmaxf(sqrtf(ss1), 1e-12f);
  const float inv2 = 1.0f / fmaxf(sqrtf(ss2), 1e-12f);
  float a[8], bb[8];
  float dot = 0.f;
#pragma unroll
  for (int j = 0; j < 8; ++j) {
    a[j] = f1[j] * inv1; bb[j] = f2[j] * inv2;
    dot += a[j] * bb[j];
  }
  int lo1 = __builtin_amdgcn_cvt_pk_fp8_f32(a[0], a[1], 0, false);
  lo1 = __builtin_amdgcn_cvt_pk_fp8_f32(a[2], a[3], lo1, true);
  int hi1 = __builtin_amdgcn_cvt_pk_fp8_f32(a[4], a[5], 0, false);
  hi1 = __builtin_amdgcn_cvt_pk_fp8_f32(a[6], a[7], hi1, true);
  int lo2 = __builtin_amdgcn_cvt_pk_fp8_f32(bb[0], bb[1], 0, false);
  lo2 = __builtin_amdgcn_cvt_pk_fp8_f32(bb[2], bb[3], lo2, true);
  int hi2 = __builtin_amdgcn_cvt_pk_fp8_f32(bb[4], bb[5], 0, false);
  hi2 = __builtin_amdgcn_cvt_pk_fp8_f32(bb[6], bb[7], hi2, true);

  // fragment-major dst: panel = row>>5, kt = c0>>6, sub = (c0>>4)&3
  const int c0 = lane * 8;
  const size_t dst = (size_t)(row >> 5) * 16384 + (c0 >> 6) * 2048
                   + ((c0 >> 4) & 3) * 512 + (row & 31) * 16 + (c0 & 15);
  *(int2*)(q1 + dst) = make_int2(lo1, hi1);
  *(int2*)(q2 + dst) = make_int2(lo2, hi2);
#pragma unroll
  for (int d = 1; d < 64; d <<= 1) dot += __shfl_xor(dot, d, 64);
  if (lane == 0) cdiag[row] = dot;
}

// ---------------- final scalar loss ----------------
__global__ __launch_bounds__(256)
void finalize_kernel(const float* __restrict__ d11, const float* __restrict__ d22,
                     const float* __restrict__ d12r, const float* __restrict__ d12c,
                     const float* __restrict__ cdiag, float* __restrict__ out) {
  const float e2 = 7.38905609893065f;
  float s = 0.f;
  for (int i = threadIdx.x; i < 8192; i += 256) {
    const float den1 = d11[i] + d12r[i] - e2;
    const float den2 = d22[i] + d12c[i] - e2;
    s += -2.0f * cdiag[i] + 0.5f * (logf(den1) + logf(den2));
  }
#pragma unroll
  for (int d = 1; d < 64; d <<= 1) s += __shfl_xor(s, d, 64);
  __shared__ float sm[4];
  if ((threadIdx.x & 63) == 0) sm[threadIdx.x >> 6] = s;
  __syncthreads();
  if (threadIdx.x == 0) out[0] = (sm[0] + sm[1] + sm[2] + sm[3]) * (1.0f / 8192.0f);
}

extern "C" void kernel_launch(void* const* d_in, const int* in_sizes, int n_in,
                              void* d_out, int out_size, void* d_ws, size_t ws_size,
                              hipStream_t stream) {
  const float* z1 = (const float*)d_in[0];
  const float* z2 = (const float*)d_in[1];
  const float* w1 = (const float*)d_in[2];
  const float* b1 = (const float*)d_in[3];
  const float* w2 = (const float*)d_in[4];
  const float* b2 = (const float*)d_in[5];
  float* out = (float*)d_out;

  const int N = 8192, D = 512;
  char* ws = (char*)d_ws;
  auto alloc = [&](size_t bytes) {
    char* p = ws; ws += (bytes + 255) & ~(size_t)255; return p;
  };
  unsigned short* z1b = (unsigned short*)alloc((size_t)N * D * 2);
  unsigned short* z2b = (unsigned short*)alloc((size_t)N * D * 2);
  unsigned short* g1  = (unsigned short*)alloc((size_t)N * D * 2);
  unsigned short* g2  = (unsigned short*)alloc((size_t)N * D * 2);
  unsigned short* w1b = (unsigned short*)alloc((size_t)D * D * 2);
  unsigned short* w2b = (unsigned short*)alloc((size_t)D * D * 2);
  float* sums  = (float*)alloc((size_t)4 * N * sizeof(float));
  float* cdiag = (float*)alloc((size_t)N * sizeof(float));
  float* d11 = sums, *d22 = sums + N, *d12r = sums + 2 * N, *d12c = sums + 3 * N;
  unsigned short* h1 = z1b;                 // stage-2 out aliases z buffers
  unsigned short* h2 = z2b;
  unsigned char* q1 = (unsigned char*)g1;   // fp8 aliases g (dead after proj2)
  unsigned char* q2 = (unsigned char*)g2;

  hipMemsetAsync(sums, 0, (size_t)4 * N * sizeof(float), stream);

  cast_all_kernel<<<dim3(8704), 256, 0, stream>>>(z1, z2, w1, w2, z1b, z2b, w1b, w2b);
  proj_kernel<0><<<dim3(1024), 256, 0, stream>>>(z1b, z2b, w1b, b1, g1, g2);
  proj_kernel<1><<<dim3(1024), 256, 0, stream>>>(g1, g2, w2b, b2, h1, h2);
  norm_diag_kernel<<<dim3(N / 4), 256, 0, stream>>>(h1, h2, q1, q2, cdiag);
  gram_kernel<<<dim3(2112), 512, 0, stream>>>(q1, q2, d11, d22, d12r, d12c);
  finalize_kernel<<<1, 256, 0, stream>>>(d11, d22, d12r, d12c, cdiag, out);
}